// Round 5
// baseline (133.086 us; speedup 1.0000x reference)
//
#include <hip/hip_runtime.h>
#include <math.h>

// VoltageNet, round 5: per-block 1-D LUT over soc.
//   KEY INSIGHT: within a block (one battery), MLP input = (soc, R0, Tmean) with
//   R0, Tmean per-block constants -> the whole chain soc -> MLP -> theta ->
//   (OCV, R1, C) is a 1-D function of soc. In-block soc span ~0.04 (random walk
//   of ~5e-5 steps); curvature tiny -> 128-node piecewise-linear LUT has ~1e-9
//   interp error. Nodes use the EXACT reference math (runs 128x/block, free).
//   Per element: idx fma + 2x ds_read_b128 + 3 lerps + affine update (~25 VALU)
//   vs ~500 issue-cycles in R1-R4. Kernel should flip to memory-bound.
//   R3/R4 lesson: bound by total issue cycles; occupancy/trans-tuning neutral.
//   UH == 0 identically (theta[3]=theta[4]=0 since LB==UB==0) -> 1-state affine
//   recurrence, parallelized as an affine-map scan.

#define TT    8192
#define BLK   1024
#define NW    16
#define EPT   8
#define NNODE 128

__device__ __forceinline__ float frcp(float x) { return __builtin_amdgcn_rcpf(x); }
__device__ __forceinline__ float fsig(float x) { return frcp(1.0f + __expf(-x)); }
__device__ __forceinline__ float ftanh_x(float x) {          // exact-enough tanh
    return 1.0f - 2.0f * frcp(__expf(2.0f * x) + 1.0f);     // saturates correctly
}
__device__ __forceinline__ float fsoftplus_x(float z) {      // true softplus
    return fmaxf(z, 0.0f) + __logf(1.0f + __expf(-fabsf(z)));
}

// Exact reference chain at one soc value (per-block constants folded in pre1).
__device__ __forceinline__ void eval_chain(float soc,
    const float* __restrict__ w1, const float* __restrict__ pre1,
    const float* __restrict__ w2, const float* __restrict__ bb2,
    float& OCV, float& R1, float& C, float& OCVU)
{
    float h[6];
    #pragma unroll
    for (int i = 0; i < 6; ++i)
        h[i] = fsoftplus_x(fmaf(soc, w1[i], pre1[i]));
    float p0 = bb2[0], p1 = bb2[1], p2 = bb2[2], p5 = bb2[5], p6 = bb2[6];
    #pragma unroll
    for (int i = 0; i < 6; ++i) {
        p0 = fmaf(h[i], w2[7*i + 0], p0);
        p1 = fmaf(h[i], w2[7*i + 1], p1);
        p2 = fmaf(h[i], w2[7*i + 2], p2);
        p5 = fmaf(h[i], w2[7*i + 5], p5);
        p6 = fmaf(h[i], w2[7*i + 6], p6);
    }
    R1   = 0.04f * fsig(0.01f * p0);
    C    = 1e-6f * fsig(0.01f * p1);
    OCVU = fmaf(0.75f,    fsig(0.01f * p2), 0.05f);
    float ox = fmaf(0.79764f, fsig(0.01f * p5), 0.04236f);
    float oy = fmaf(0.82504f, fsig(0.01f * p6), 0.023f);
    // Up(oy): full reference incl. the exp knee
    float up = fmaf(oy, fmaf(oy, fmaf(oy, fmaf(oy, fmaf(oy, -2.2166f, 3.5146f),
                    -2.0843f), 1.6225f), -1.6518f), 4.4167f);
    up -= 4.0f * __expf(fmaf(109.451f, oy, -100.006f));
    // Un(ox): full reference
    float un = 0.063f + 0.8f * __expf(-75.0f * (ox + 0.001f));
    un = fmaf(-0.012f,  ftanh_x((ox - 0.127f) * 62.5f),        un);
    un = fmaf(-0.0118f, ftanh_x((ox - 0.155f) * 62.5f),        un);
    un = fmaf(-0.0035f, ftanh_x((ox - 0.22f)  * 50.0f),        un);
    un = fmaf(-0.0095f, ftanh_x((ox - 0.19f)  * 76.9230769f),  un);
    un = fmaf(-0.0145f, ftanh_x((ox - 0.49f)  * 50.0f),        un);
    un = fmaf(-0.08f,   ftanh_x((ox - 1.03f)  * 18.1818182f),  un);
    OCV = up - un;
}

__global__ void __launch_bounds__(BLK, 8)
voltnet_kernel(const float* __restrict__ X, const float* __restrict__ SC,
               const float* __restrict__ W1, const float* __restrict__ b1,
               const float* __restrict__ W2, const float* __restrict__ b2,
               float* __restrict__ out)
{
    __shared__ float  tw[NW], dw[NW], mnw[NW], mxw[NW], sA[NW], sB[NW];
    __shared__ float4 nodes[NNODE];
    __shared__ float  bcU10;

    const int b    = blockIdx.x;
    const int tid  = threadIdx.x;
    const int lane = tid & 63;
    const int wv   = tid >> 6;
    const int s    = tid * EPT;

    const float* __restrict__ Xrow = X + (size_t)b * TT * 3;
    const float Q  = SC[2 * b + 0];
    const float R0 = SC[2 * b + 1];

    // weights -> uniform (SGPR) loads
    float w1[18], bb1[6], w2[42], bb2[7];
    #pragma unroll
    for (int i = 0; i < 18; ++i) w1[i] = W1[i];
    #pragma unroll
    for (int i = 0; i < 6;  ++i) bb1[i] = b1[i];
    #pragma unroll
    for (int i = 0; i < 42; ++i) w2[i] = W2[i];
    #pragma unroll
    for (int i = 0; i < 7;  ++i) bb2[i] = b2[i];

    // ---- Phase 0: per-thread contiguous loads, register SOC prefix, Tsum ----
    float Ireg[EPT], lp[EPT];
    float tsum = 0.0f, run = 0.0f;
    float mnl = 1e30f, mxl = -1e30f;
    float tprev = 0.0f, iprev = 0.0f;
    if (tid > 0) { tprev = Xrow[3 * s - 3]; iprev = Xrow[3 * s - 2]; }
    const float inext_last = (tid < BLK - 1) ? Xrow[3 * (s + EPT) + 1] : 0.0f;

    const float4* __restrict__ Xv = (const float4*)(Xrow + 3 * s);  // 96B/thread
    #pragma unroll
    for (int c = 0; c < 2; ++c) {
        float4 q0 = Xv[3 * c + 0], q1 = Xv[3 * c + 1], q2 = Xv[3 * c + 2];
        float f[12] = { q0.x, q0.y, q0.z, q0.w, q1.x, q1.y,
                        q1.z, q1.w, q2.x, q2.y, q2.z, q2.w };
        #pragma unroll
        for (int u = 0; u < 4; ++u) {
            int e = 4 * c + u;
            float tt = f[3 * u + 0];
            float ii = f[3 * u + 1];
            float ds = (ii + iprev) * (tt - tprev) * (1.0f / 36000.0f);
            if (e == 0 && tid == 0) ds = 0.0f;
            run += ds;
            lp[e]   = run;
            Ireg[e] = ii;
            mnl = fminf(mnl, run);
            mxl = fmaxf(mxl, run);
            tsum += f[3 * u + 2];
            tprev = tt; iprev = ii;
        }
    }

    // wave reduce tsum; wave inclusive scan of thread totals
    float ts = tsum;
    #pragma unroll
    for (int d = 32; d > 0; d >>= 1) ts += __shfl_down(ts, d, 64);
    float inc = run;
    #pragma unroll
    for (int d = 1; d < 64; d <<= 1) {
        float v = __shfl_up(inc, d, 64);
        if (lane >= d) inc += v;
    }
    if (lane == 0)  tw[wv] = ts;
    if (lane == 63) dw[wv] = inc;
    __syncthreads();                                    // S1

    float Tsum = 0.0f;
    #pragma unroll
    for (int w = 0; w < NW; ++w) Tsum += tw[w];
    const float Tmean = Tsum * (1.0f / (float)TT);
    float woff = 0.0f;
    for (int w = 0; w < wv; ++w) woff += dw[w];         // wave-uniform
    const float soc_base = fmaf(Q, 0.2f, woff + (inc - run));

    // block min/max of soc
    float mn_t = soc_base + mnl, mx_t = soc_base + mxl;
    #pragma unroll
    for (int d = 32; d > 0; d >>= 1) {
        mn_t = fminf(mn_t, __shfl_down(mn_t, d, 64));
        mx_t = fmaxf(mx_t, __shfl_down(mx_t, d, 64));
    }
    if (lane == 0) { mnw[wv] = mn_t; mxw[wv] = mx_t; }
    __syncthreads();                                    // S2
    float lo = 1e30f, hi = -1e30f;
    #pragma unroll
    for (int w = 0; w < NW; ++w) { lo = fminf(lo, mnw[w]); hi = fmaxf(hi, mxw[w]); }
    {
        float pad = fmaf(hi - lo, 1.0f / 256.0f, 1e-7f);
        lo -= pad; hi += pad;
    }
    const float hstep = (hi - lo) * (1.0f / (float)(NNODE - 1));
    const float invh  = (float)(NNODE - 1) * frcp(hi - lo);

    float pre1[6];
    #pragma unroll
    for (int o = 0; o < 6; ++o)
        pre1[o] = fmaf(R0, w1[6 + o], fmaf(Tmean, w1[12 + o], bb1[o]));

    // ---- Node evaluation: exact reference chain at 128 soc nodes ----
    if (tid < NNODE) {
        float OCV, R1v, Cv, OCVU;
        eval_chain(fmaf((float)tid, hstep, lo), w1, pre1, w2, bb2, OCV, R1v, Cv, OCVU);
        nodes[tid] = make_float4(OCV, R1v, Cv, 0.0f);
    }
    if (tid == 0) {
        float OCV, R1v, Cv, OCVU;
        eval_chain(soc_base, w1, pre1, w2, bb2, OCV, R1v, Cv, OCVU);  // soc at j=0
        bcU10 = -OCVU - Ireg[0] * R0;
    }
    __syncthreads();                                    // S3

    // ---- Phase 2: LUT interp + affine recurrence coefficients ----
    float Ap = 1.0f, Bp = 0.0f;
    #pragma unroll
    for (int e = 0; e < EPT; ++e) {
        float soc = soc_base + lp[e];
        float u   = (soc - lo) * invh;
        int   k   = (int)u;
        k = (k < 0) ? 0 : ((k > NNODE - 2) ? NNODE - 2 : k);
        float fr  = u - (float)k;
        float4 n0 = nodes[k];
        float4 n1 = nodes[k + 1];
        float OCV = fmaf(fr, n1.x - n0.x, n0.x);
        float R1v = fmaf(fr, n1.y - n0.y, n0.y);
        float Cv  = fmaf(fr, n1.z - n0.z, n0.z);

        float ii  = Ireg[e];
        float inx = (e == EPT - 1) ? inext_last : Ireg[e + 1];

        // stash: pred[j] = P + Apre * U1_at_thread_start   (UH == 0)
        lp[e]   = fmaf(ii, R0, OCV) + Bp;
        Ireg[e] = Ap;

        float g  = (inx - ii) * Cv;
        float aj = 1.0f - g;
        float bj = g * R1v * ii;
        if (e == EPT - 1) {                  // only the global last step is masked
            bool last = (tid == BLK - 1);
            aj = last ? 1.0f : aj;
            bj = last ? 0.0f : bj;
        }
        Bp = fmaf(aj, Bp, bj);
        Ap = aj * Ap;
    }

    // ---- affine block scan ((a2,b2)o(a1,b1) = (a2*a1, a2*b1+b2)) ----
    float A = Ap, B = Bp;
    #pragma unroll
    for (int d = 1; d < 64; d <<= 1) {
        float Au = __shfl_up(A, d, 64);
        float Bu = __shfl_up(B, d, 64);
        if (lane >= d) { B = fmaf(A, Bu, B); A = A * Au; }
    }
    float Aex = __shfl_up(A, 1, 64);
    float Bex = __shfl_up(B, 1, 64);
    if (lane == 0) { Aex = 1.0f; Bex = 0.0f; }
    if (lane == 63) { sA[wv] = A; sB[wv] = B; }
    __syncthreads();                                    // S4
    float Ao = 1.0f, Bo = 0.0f;
    for (int w = 0; w < wv; ++w) {                      // wave-uniform
        Bo = fmaf(sA[w], Bo, sB[w]);
        Ao = sA[w] * Ao;
    }
    const float U1s = fmaf(Aex * Ao, bcU10, fmaf(Aex, Bo, Bex));

    // ---- Phase 3: per-thread contiguous float4 stores ----
    float4* __restrict__ Ov = (float4*)(out + (size_t)b * TT + s);  // 32B-aligned
    #pragma unroll
    for (int c = 0; c < 2; ++c) {
        float4 o;
        o.x = fmaf(Ireg[4 * c + 0], U1s, lp[4 * c + 0]);
        o.y = fmaf(Ireg[4 * c + 1], U1s, lp[4 * c + 1]);
        o.z = fmaf(Ireg[4 * c + 2], U1s, lp[4 * c + 2]);
        o.w = fmaf(Ireg[4 * c + 3], U1s, lp[4 * c + 3]);
        Ov[c] = o;
    }
}

extern "C" void kernel_launch(void* const* d_in, const int* in_sizes, int n_in,
                              void* d_out, int out_size, void* d_ws, size_t ws_size,
                              hipStream_t stream)
{
    const float* X  = (const float*)d_in[0];
    const float* SC = (const float*)d_in[1];
    const float* W1 = (const float*)d_in[2];
    const float* b1 = (const float*)d_in[3];
    const float* W2 = (const float*)d_in[4];
    const float* b2 = (const float*)d_in[5];
    float* outp = (float*)d_out;
    const int B = in_sizes[1] / 2;   // SC is (B,2)
    hipLaunchKernelGGL(voltnet_kernel, dim3(B), dim3(BLK), 0, stream,
                       X, SC, W1, b1, W2, b2, outp);
}

// Round 6
// 107.891 us; speedup vs baseline: 1.2335x; 1.2335x over previous
//
#include <hip/hip_runtime.h>
#include <math.h>

// VoltageNet, round 6: R5 LUT kernel with the spill bug fixed.
//   R5 post-mortem: __launch_bounds__(1024,8) capped VGPR at 64 (allocator chose
//   32) -> ~60-reg working set spilled to scratch: WRITE_SIZE 16->96 MB,
//   FETCH 25->70 MB, VALUBusy 13%. The LUT itself was correct (absmax 0.0625).
//   Single change: launch_bounds(1024,4) -> VGPR cap 128, no spills.
//   KEY INSIGHT (R5): within a block, (R0,Tmean) are constants -> chain
//   soc -> MLP -> theta -> (OCV,R1,C) is a 1-D function of soc; in-block soc
//   span ~0.04 -> 128-node piecewise-linear LUT, nodes use EXACT reference math.
//   UH == 0 identically (theta[3]=theta[4]=0 since LB==UB==0) -> 1-state affine
//   recurrence, parallelized as an affine-map scan.

#define TT    8192
#define BLK   1024
#define NW    16
#define EPT   8
#define NNODE 128

__device__ __forceinline__ float frcp(float x) { return __builtin_amdgcn_rcpf(x); }
__device__ __forceinline__ float fsig(float x) { return frcp(1.0f + __expf(-x)); }
__device__ __forceinline__ float ftanh_x(float x) {
    return 1.0f - 2.0f * frcp(__expf(2.0f * x) + 1.0f);
}
__device__ __forceinline__ float fsoftplus_x(float z) {
    return fmaxf(z, 0.0f) + __logf(1.0f + __expf(-fabsf(z)));
}

// Exact reference chain at one soc value (per-block constants folded in pre1).
__device__ __forceinline__ void eval_chain(float soc,
    const float* __restrict__ w1, const float* __restrict__ pre1,
    const float* __restrict__ w2, const float* __restrict__ bb2,
    float& OCV, float& R1, float& C, float& OCVU)
{
    float h[6];
    #pragma unroll
    for (int i = 0; i < 6; ++i)
        h[i] = fsoftplus_x(fmaf(soc, w1[i], pre1[i]));
    float p0 = bb2[0], p1 = bb2[1], p2 = bb2[2], p5 = bb2[5], p6 = bb2[6];
    #pragma unroll
    for (int i = 0; i < 6; ++i) {
        p0 = fmaf(h[i], w2[7*i + 0], p0);
        p1 = fmaf(h[i], w2[7*i + 1], p1);
        p2 = fmaf(h[i], w2[7*i + 2], p2);
        p5 = fmaf(h[i], w2[7*i + 5], p5);
        p6 = fmaf(h[i], w2[7*i + 6], p6);
    }
    R1   = 0.04f * fsig(0.01f * p0);
    C    = 1e-6f * fsig(0.01f * p1);
    OCVU = fmaf(0.75f,    fsig(0.01f * p2), 0.05f);
    float ox = fmaf(0.79764f, fsig(0.01f * p5), 0.04236f);
    float oy = fmaf(0.82504f, fsig(0.01f * p6), 0.023f);
    float up = fmaf(oy, fmaf(oy, fmaf(oy, fmaf(oy, fmaf(oy, -2.2166f, 3.5146f),
                    -2.0843f), 1.6225f), -1.6518f), 4.4167f);
    up -= 4.0f * __expf(fmaf(109.451f, oy, -100.006f));
    float un = 0.063f + 0.8f * __expf(-75.0f * (ox + 0.001f));
    un = fmaf(-0.012f,  ftanh_x((ox - 0.127f) * 62.5f),        un);
    un = fmaf(-0.0118f, ftanh_x((ox - 0.155f) * 62.5f),        un);
    un = fmaf(-0.0035f, ftanh_x((ox - 0.22f)  * 50.0f),        un);
    un = fmaf(-0.0095f, ftanh_x((ox - 0.19f)  * 76.9230769f),  un);
    un = fmaf(-0.0145f, ftanh_x((ox - 0.49f)  * 50.0f),        un);
    un = fmaf(-0.08f,   ftanh_x((ox - 1.03f)  * 18.1818182f),  un);
    OCV = up - un;
}

__global__ void __launch_bounds__(BLK, 4)
voltnet_kernel(const float* __restrict__ X, const float* __restrict__ SC,
               const float* __restrict__ W1, const float* __restrict__ b1,
               const float* __restrict__ W2, const float* __restrict__ b2,
               float* __restrict__ out)
{
    __shared__ float  tw[NW], dw[NW], mnw[NW], mxw[NW], sA[NW], sB[NW];
    __shared__ float4 nodes[NNODE];
    __shared__ float  bcU10;

    const int b    = blockIdx.x;
    const int tid  = threadIdx.x;
    const int lane = tid & 63;
    const int wv   = tid >> 6;
    const int s    = tid * EPT;

    const float* __restrict__ Xrow = X + (size_t)b * TT * 3;
    const float Q  = SC[2 * b + 0];
    const float R0 = SC[2 * b + 1];

    // weights -> uniform (SGPR) loads
    float w1[18], bb1[6], w2[42], bb2[7];
    #pragma unroll
    for (int i = 0; i < 18; ++i) w1[i] = W1[i];
    #pragma unroll
    for (int i = 0; i < 6;  ++i) bb1[i] = b1[i];
    #pragma unroll
    for (int i = 0; i < 42; ++i) w2[i] = W2[i];
    #pragma unroll
    for (int i = 0; i < 7;  ++i) bb2[i] = b2[i];

    // ---- Phase 0: per-thread contiguous loads, register SOC prefix, Tsum ----
    float Ireg[EPT], lp[EPT];
    float tsum = 0.0f, run = 0.0f;
    float mnl = 1e30f, mxl = -1e30f;
    float tprev = 0.0f, iprev = 0.0f;
    if (tid > 0) { tprev = Xrow[3 * s - 3]; iprev = Xrow[3 * s - 2]; }
    const float inext_last = (tid < BLK - 1) ? Xrow[3 * (s + EPT) + 1] : 0.0f;

    const float4* __restrict__ Xv = (const float4*)(Xrow + 3 * s);  // 96B/thread
    #pragma unroll
    for (int c = 0; c < 2; ++c) {
        float4 q0 = Xv[3 * c + 0], q1 = Xv[3 * c + 1], q2 = Xv[3 * c + 2];
        float f[12] = { q0.x, q0.y, q0.z, q0.w, q1.x, q1.y,
                        q1.z, q1.w, q2.x, q2.y, q2.z, q2.w };
        #pragma unroll
        for (int u = 0; u < 4; ++u) {
            int e = 4 * c + u;
            float tt = f[3 * u + 0];
            float ii = f[3 * u + 1];
            float ds = (ii + iprev) * (tt - tprev) * (1.0f / 36000.0f);
            if (e == 0 && tid == 0) ds = 0.0f;
            run += ds;
            lp[e]   = run;
            Ireg[e] = ii;
            mnl = fminf(mnl, run);
            mxl = fmaxf(mxl, run);
            tsum += f[3 * u + 2];
            tprev = tt; iprev = ii;
        }
    }

    // wave reduce tsum; wave inclusive scan of thread totals
    float ts = tsum;
    #pragma unroll
    for (int d = 32; d > 0; d >>= 1) ts += __shfl_down(ts, d, 64);
    float inc = run;
    #pragma unroll
    for (int d = 1; d < 64; d <<= 1) {
        float v = __shfl_up(inc, d, 64);
        if (lane >= d) inc += v;
    }
    if (lane == 0)  tw[wv] = ts;
    if (lane == 63) dw[wv] = inc;
    __syncthreads();                                    // S1

    float Tsum = 0.0f;
    #pragma unroll
    for (int w = 0; w < NW; ++w) Tsum += tw[w];
    const float Tmean = Tsum * (1.0f / (float)TT);
    float woff = 0.0f;
    for (int w = 0; w < wv; ++w) woff += dw[w];         // wave-uniform
    const float soc_base = fmaf(Q, 0.2f, woff + (inc - run));

    // block min/max of soc
    float mn_t = soc_base + mnl, mx_t = soc_base + mxl;
    #pragma unroll
    for (int d = 32; d > 0; d >>= 1) {
        mn_t = fminf(mn_t, __shfl_down(mn_t, d, 64));
        mx_t = fmaxf(mx_t, __shfl_down(mx_t, d, 64));
    }
    if (lane == 0) { mnw[wv] = mn_t; mxw[wv] = mx_t; }
    __syncthreads();                                    // S2
    float lo = 1e30f, hi = -1e30f;
    #pragma unroll
    for (int w = 0; w < NW; ++w) { lo = fminf(lo, mnw[w]); hi = fmaxf(hi, mxw[w]); }
    {
        float pad = fmaf(hi - lo, 1.0f / 256.0f, 1e-7f);
        lo -= pad; hi += pad;
    }
    const float hstep = (hi - lo) * (1.0f / (float)(NNODE - 1));
    const float invh  = (float)(NNODE - 1) * frcp(hi - lo);

    float pre1[6];
    #pragma unroll
    for (int o = 0; o < 6; ++o)
        pre1[o] = fmaf(R0, w1[6 + o], fmaf(Tmean, w1[12 + o], bb1[o]));

    // ---- Node evaluation: exact reference chain at 128 soc nodes ----
    if (tid < NNODE) {
        float OCV, R1v, Cv, OCVU;
        eval_chain(fmaf((float)tid, hstep, lo), w1, pre1, w2, bb2, OCV, R1v, Cv, OCVU);
        nodes[tid] = make_float4(OCV, R1v, Cv, 0.0f);
    }
    if (tid == 0) {
        float OCV, R1v, Cv, OCVU;
        eval_chain(soc_base, w1, pre1, w2, bb2, OCV, R1v, Cv, OCVU);  // soc at j=0
        bcU10 = -OCVU - Ireg[0] * R0;
    }
    __syncthreads();                                    // S3

    // ---- Phase 2: LUT interp + affine recurrence coefficients ----
    float Ap = 1.0f, Bp = 0.0f;
    #pragma unroll
    for (int e = 0; e < EPT; ++e) {
        float soc = soc_base + lp[e];
        float u   = (soc - lo) * invh;
        int   k   = (int)u;
        k = (k < 0) ? 0 : ((k > NNODE - 2) ? NNODE - 2 : k);
        float fr  = u - (float)k;
        float4 n0 = nodes[k];
        float4 n1 = nodes[k + 1];
        float OCV = fmaf(fr, n1.x - n0.x, n0.x);
        float R1v = fmaf(fr, n1.y - n0.y, n0.y);
        float Cv  = fmaf(fr, n1.z - n0.z, n0.z);

        float ii  = Ireg[e];
        float inx = (e == EPT - 1) ? inext_last : Ireg[e + 1];

        // stash: pred[j] = P + Apre * U1_at_thread_start   (UH == 0)
        lp[e]   = fmaf(ii, R0, OCV) + Bp;
        Ireg[e] = Ap;

        float g  = (inx - ii) * Cv;
        float aj = 1.0f - g;
        float bj = g * R1v * ii;
        if (e == EPT - 1) {                  // only the global last step is masked
            bool last = (tid == BLK - 1);
            aj = last ? 1.0f : aj;
            bj = last ? 0.0f : bj;
        }
        Bp = fmaf(aj, Bp, bj);
        Ap = aj * Ap;
    }

    // ---- affine block scan ((a2,b2)o(a1,b1) = (a2*a1, a2*b1+b2)) ----
    float A = Ap, B = Bp;
    #pragma unroll
    for (int d = 1; d < 64; d <<= 1) {
        float Au = __shfl_up(A, d, 64);
        float Bu = __shfl_up(B, d, 64);
        if (lane >= d) { B = fmaf(A, Bu, B); A = A * Au; }
    }
    float Aex = __shfl_up(A, 1, 64);
    float Bex = __shfl_up(B, 1, 64);
    if (lane == 0) { Aex = 1.0f; Bex = 0.0f; }
    if (lane == 63) { sA[wv] = A; sB[wv] = B; }
    __syncthreads();                                    // S4
    float Ao = 1.0f, Bo = 0.0f;
    for (int w = 0; w < wv; ++w) {                      // wave-uniform
        Bo = fmaf(sA[w], Bo, sB[w]);
        Ao = sA[w] * Ao;
    }
    const float U1s = fmaf(Aex * Ao, bcU10, fmaf(Aex, Bo, Bex));

    // ---- Phase 3: per-thread contiguous float4 stores ----
    float4* __restrict__ Ov = (float4*)(out + (size_t)b * TT + s);  // 32B-aligned
    #pragma unroll
    for (int c = 0; c < 2; ++c) {
        float4 o;
        o.x = fmaf(Ireg[4 * c + 0], U1s, lp[4 * c + 0]);
        o.y = fmaf(Ireg[4 * c + 1], U1s, lp[4 * c + 1]);
        o.z = fmaf(Ireg[4 * c + 2], U1s, lp[4 * c + 2]);
        o.w = fmaf(Ireg[4 * c + 3], U1s, lp[4 * c + 3]);
        Ov[c] = o;
    }
}

extern "C" void kernel_launch(void* const* d_in, const int* in_sizes, int n_in,
                              void* d_out, int out_size, void* d_ws, size_t ws_size,
                              hipStream_t stream)
{
    const float* X  = (const float*)d_in[0];
    const float* SC = (const float*)d_in[1];
    const float* W1 = (const float*)d_in[2];
    const float* b1 = (const float*)d_in[3];
    const float* W2 = (const float*)d_in[4];
    const float* b2 = (const float*)d_in[5];
    float* outp = (float*)d_out;
    const int B = in_sizes[1] / 2;   // SC is (B,2)
    hipLaunchKernelGGL(voltnet_kernel, dim3(B), dim3(BLK), 0, stream,
                       X, SC, W1, b1, W2, b2, outp);
}

// Round 7
// 104.237 us; speedup vs baseline: 1.2768x; 1.0351x over previous
//
#include <hip/hip_runtime.h>
#include <math.h>

// VoltageNet, round 7: R6's per-block soc-LUT + R3's coalesced LDS-staged moves.
//   R6 post-mortem: kernel ~30us, VALU idle, real traffic 67MB (~11us floor).
//   Remaining cost: per-thread-chunk loads (96B lane stride -> ~96 lines/instr
//   vs 16 coalesced = ~6x TA work) + 32B-stride stores. Fix: lane-interleaved
//   scalar loads (12B stride, contiguous per wave-triple) staged through LDS
//   for the ownership transpose (R1/R3 pattern), LUT math kept, nontemporal
//   coalesced stores.
//   KEY INSIGHT (R5): per block, (R0,Tmean) const -> soc -> (OCV,R1,C) is 1-D;
//   128-node piecewise-linear LUT with EXACT reference math at nodes.
//   UH == 0 identically (theta[3]=theta[4]=0 since LB==UB==0) -> 1-state affine
//   recurrence, parallelized as an affine-map scan.
//   R5 lesson: never declare launch_bounds that caps VGPR below working set.

#define TT    8192
#define BLK   512
#define NW    8
#define EPT   16
#define NNODE 128
#define PADJ(j) ((j) + ((j) >> 5))

__device__ __forceinline__ float frcp(float x) { return __builtin_amdgcn_rcpf(x); }
__device__ __forceinline__ float fsig(float x) { return frcp(1.0f + __expf(-x)); }
__device__ __forceinline__ float ftanh_x(float x) {
    return 1.0f - 2.0f * frcp(__expf(2.0f * x) + 1.0f);
}
__device__ __forceinline__ float fsoftplus_x(float z) {
    return fmaxf(z, 0.0f) + __logf(1.0f + __expf(-fabsf(z)));
}

// Exact reference chain at one soc value (per-block constants folded in pre1).
__device__ __forceinline__ void eval_chain(float soc,
    const float* __restrict__ w1, const float* __restrict__ pre1,
    const float* __restrict__ w2, const float* __restrict__ bb2,
    float& OCV, float& R1, float& C, float& OCVU)
{
    float h[6];
    #pragma unroll
    for (int i = 0; i < 6; ++i)
        h[i] = fsoftplus_x(fmaf(soc, w1[i], pre1[i]));
    float p0 = bb2[0], p1 = bb2[1], p2 = bb2[2], p5 = bb2[5], p6 = bb2[6];
    #pragma unroll
    for (int i = 0; i < 6; ++i) {
        p0 = fmaf(h[i], w2[7*i + 0], p0);
        p1 = fmaf(h[i], w2[7*i + 1], p1);
        p2 = fmaf(h[i], w2[7*i + 2], p2);
        p5 = fmaf(h[i], w2[7*i + 5], p5);
        p6 = fmaf(h[i], w2[7*i + 6], p6);
    }
    R1   = 0.04f * fsig(0.01f * p0);
    C    = 1e-6f * fsig(0.01f * p1);
    OCVU = fmaf(0.75f,    fsig(0.01f * p2), 0.05f);
    float ox = fmaf(0.79764f, fsig(0.01f * p5), 0.04236f);
    float oy = fmaf(0.82504f, fsig(0.01f * p6), 0.023f);
    float up = fmaf(oy, fmaf(oy, fmaf(oy, fmaf(oy, fmaf(oy, -2.2166f, 3.5146f),
                    -2.0843f), 1.6225f), -1.6518f), 4.4167f);
    up -= 4.0f * __expf(fmaf(109.451f, oy, -100.006f));
    float un = 0.063f + 0.8f * __expf(-75.0f * (ox + 0.001f));
    un = fmaf(-0.012f,  ftanh_x((ox - 0.127f) * 62.5f),        un);
    un = fmaf(-0.0118f, ftanh_x((ox - 0.155f) * 62.5f),        un);
    un = fmaf(-0.0035f, ftanh_x((ox - 0.22f)  * 50.0f),        un);
    un = fmaf(-0.0095f, ftanh_x((ox - 0.19f)  * 76.9230769f),  un);
    un = fmaf(-0.0145f, ftanh_x((ox - 0.49f)  * 50.0f),        un);
    un = fmaf(-0.08f,   ftanh_x((ox - 1.03f)  * 18.1818182f),  un);
    OCV = up - un;
}

__global__ void __launch_bounds__(BLK, 4)
voltnet_kernel(const float* __restrict__ X, const float* __restrict__ SC,
               const float* __restrict__ W1, const float* __restrict__ b1,
               const float* __restrict__ W2, const float* __restrict__ b2,
               float* __restrict__ out)
{
    __shared__ float  ldsT[PADJ(TT - 1) + 2];   // t -> local dSOC prefix -> stash P
    __shared__ float  ldsI[PADJ(TT - 1) + 2];   // I ............-> stash Apre
    __shared__ float  tw[NW], dw[NW], mnw[NW], mxw[NW], sA[NW], sB[NW];
    __shared__ float4 nodes[NNODE];
    __shared__ float  U1arr[BLK];
    __shared__ float  bcU10;

    const int b    = blockIdx.x;
    const int tid  = threadIdx.x;
    const int lane = tid & 63;
    const int wv   = tid >> 6;
    const int s    = tid * EPT;

    const float* __restrict__ Xrow = X + (size_t)b * TT * 3;
    const float Q  = SC[2 * b + 0];
    const float R0 = SC[2 * b + 1];

    // weights -> uniform (SGPR) loads
    float w1[18], bb1[6], w2[42], bb2[7];
    #pragma unroll
    for (int i = 0; i < 18; ++i) w1[i] = W1[i];
    #pragma unroll
    for (int i = 0; i < 6;  ++i) bb1[i] = b1[i];
    #pragma unroll
    for (int i = 0; i < 42; ++i) w2[i] = W2[i];
    #pragma unroll
    for (int i = 0; i < 7;  ++i) bb2[i] = b2[i];

    // ---- Phase 1: coalesced (12B lane stride) load into LDS; Temp sum ----
    float tsum = 0.0f;
    #pragma unroll 4
    for (int it = 0; it < EPT; ++it) {
        int j = tid + it * BLK;
        float tt = Xrow[3 * j + 0];
        float ii = Xrow[3 * j + 1];
        float tp = Xrow[3 * j + 2];
        ldsT[PADJ(j)] = tt;
        ldsI[PADJ(j)] = ii;
        tsum += tp;
    }
    #pragma unroll
    for (int d = 32; d > 0; d >>= 1) tsum += __shfl_down(tsum, d, 64);
    if (lane == 0) tw[wv] = tsum;
    __syncthreads();                                    // S1

    float Tsum = 0.0f;
    #pragma unroll
    for (int w = 0; w < NW; ++w) Tsum += tw[w];
    const float Tmean = Tsum * (1.0f / (float)TT);

    float pre1[6];
    #pragma unroll
    for (int o = 0; o < 6; ++o)
        pre1[o] = fmaf(R0, w1[6 + o], fmaf(Tmean, w1[12 + o], bb1[o]));

    // boundary reads that phase 2a/2b will overwrite / race on — do them now
    float tprev = 0.0f, iprev = 0.0f;
    if (tid > 0) { tprev = ldsT[PADJ(s - 1)]; iprev = ldsI[PADJ(s - 1)]; }
    const float inext_last = (tid < BLK - 1) ? ldsI[PADJ(s + EPT)] : 0.0f;
    __syncthreads();                                    // S2

    // ---- Phase 2a: local dSOC prefix (in-place into ldsT); track min/max ----
    float lp = 0.0f;
    float mnl = 1e30f, mxl = -1e30f;
    #pragma unroll 4
    for (int e = 0; e < EPT; ++e) {
        int j = s + e;
        float tt = ldsT[PADJ(j)];
        float ii = ldsI[PADJ(j)];
        float ds = (ii + iprev) * (tt - tprev) * (1.0f / 36000.0f);
        if (j == 0) ds = 0.0f;
        lp += ds;
        ldsT[PADJ(j)] = lp;     // inclusive local prefix
        mnl = fminf(mnl, lp);
        mxl = fmaxf(mxl, lp);
        tprev = tt; iprev = ii;
    }
    float inc = lp;
    #pragma unroll
    for (int d = 1; d < 64; d <<= 1) {
        float v = __shfl_up(inc, d, 64);
        if (lane >= d) inc += v;
    }
    if (lane == 63) dw[wv] = inc;
    __syncthreads();                                    // S3
    float woff = 0.0f;
    for (int w = 0; w < wv; ++w) woff += dw[w];         // wave-uniform
    const float soc_base = fmaf(Q, 0.2f, woff + (inc - lp));

    // block min/max of soc
    float mn_t = soc_base + mnl, mx_t = soc_base + mxl;
    #pragma unroll
    for (int d = 32; d > 0; d >>= 1) {
        mn_t = fminf(mn_t, __shfl_down(mn_t, d, 64));
        mx_t = fmaxf(mx_t, __shfl_down(mx_t, d, 64));
    }
    if (lane == 0) { mnw[wv] = mn_t; mxw[wv] = mx_t; }
    __syncthreads();                                    // S4
    float lo = 1e30f, hi = -1e30f;
    #pragma unroll
    for (int w = 0; w < NW; ++w) { lo = fminf(lo, mnw[w]); hi = fmaxf(hi, mxw[w]); }
    {
        float pad = fmaf(hi - lo, 1.0f / 256.0f, 1e-7f);
        lo -= pad; hi += pad;
    }
    const float hstep = (hi - lo) * (1.0f / (float)(NNODE - 1));
    const float invh  = (float)(NNODE - 1) * frcp(hi - lo);

    // ---- Node evaluation: exact reference chain at 128 soc nodes ----
    if (tid < NNODE) {
        float OCV, R1v, Cv, OCVU;
        eval_chain(fmaf((float)tid, hstep, lo), w1, pre1, w2, bb2, OCV, R1v, Cv, OCVU);
        nodes[tid] = make_float4(OCV, R1v, Cv, 0.0f);
    }
    if (tid == 0) {
        float OCV, R1v, Cv, OCVU;
        eval_chain(soc_base, w1, pre1, w2, bb2, OCV, R1v, Cv, OCVU);  // soc at j=0
        bcU10 = -OCVU - ldsI[PADJ(0)] * R0;
    }
    __syncthreads();                                    // S5

    // ---- Phase 2b: LUT interp + affine coefficients; stash P/Apre in LDS ----
    float Ap = 1.0f, Bp = 0.0f;
    #pragma unroll 4
    for (int e = 0; e < EPT; ++e) {
        int j = s + e;
        float soc = soc_base + ldsT[PADJ(j)];
        float ii  = ldsI[PADJ(j)];
        float inx = (e == EPT - 1) ? inext_last : ldsI[PADJ(j + 1)];

        float u  = (soc - lo) * invh;
        int   k  = (int)u;
        k = (k < 0) ? 0 : ((k > NNODE - 2) ? NNODE - 2 : k);
        float fr = u - (float)k;
        float4 n0 = nodes[k];
        float4 n1 = nodes[k + 1];
        float OCV = fmaf(fr, n1.x - n0.x, n0.x);
        float R1v = fmaf(fr, n1.y - n0.y, n0.y);
        float Cv  = fmaf(fr, n1.z - n0.z, n0.z);

        // stash: pred[j] = P + Apre * U1_at_thread_start   (UH == 0)
        ldsT[PADJ(j)] = fmaf(ii, R0, OCV) + Bp;
        ldsI[PADJ(j)] = Ap;

        float g  = (inx - ii) * Cv;
        float aj = 1.0f - g;
        float bj = g * R1v * ii;
        if (j == TT - 1) { aj = 1.0f; bj = 0.0f; }
        Bp = fmaf(aj, Bp, bj);
        Ap = aj * Ap;
    }

    // ---- affine block scan ((a2,b2)o(a1,b1) = (a2*a1, a2*b1+b2)) ----
    float A = Ap, B = Bp;
    #pragma unroll
    for (int d = 1; d < 64; d <<= 1) {
        float Au = __shfl_up(A, d, 64);
        float Bu = __shfl_up(B, d, 64);
        if (lane >= d) { B = fmaf(A, Bu, B); A = A * Au; }
    }
    float Aex = __shfl_up(A, 1, 64);
    float Bex = __shfl_up(B, 1, 64);
    if (lane == 0) { Aex = 1.0f; Bex = 0.0f; }
    if (lane == 63) { sA[wv] = A; sB[wv] = B; }
    __syncthreads();                                    // S6
    float Ao = 1.0f, Bo = 0.0f;
    for (int w = 0; w < wv; ++w) {                      // wave-uniform
        Bo = fmaf(sA[w], Bo, sB[w]);
        Ao = sA[w] * Ao;
    }
    const float U1s = fmaf(Aex * Ao, bcU10, fmaf(Aex, Bo, Bex));
    U1arr[tid] = U1s;
    __syncthreads();                                    // S7

    // ---- Phase 3: coalesced nontemporal stores ----
    float* __restrict__ orow = out + (size_t)b * TT;
    #pragma unroll 4
    for (int it = 0; it < EPT; ++it) {
        int j = tid + it * BLK;
        float v = fmaf(ldsI[PADJ(j)], U1arr[j >> 4], ldsT[PADJ(j)]);
        __builtin_nontemporal_store(v, &orow[j]);
    }
}

extern "C" void kernel_launch(void* const* d_in, const int* in_sizes, int n_in,
                              void* d_out, int out_size, void* d_ws, size_t ws_size,
                              hipStream_t stream)
{
    const float* X  = (const float*)d_in[0];
    const float* SC = (const float*)d_in[1];
    const float* W1 = (const float*)d_in[2];
    const float* b1 = (const float*)d_in[3];
    const float* W2 = (const float*)d_in[4];
    const float* b2 = (const float*)d_in[5];
    float* outp = (float*)d_out;
    const int B = in_sizes[1] / 2;   // SC is (B,2)
    hipLaunchKernelGGL(voltnet_kernel, dim3(B), dim3(BLK), 0, stream,
                       X, SC, W1, b1, W2, b2, outp);
}